// Round 1
// 699.868 us; speedup vs baseline: 1.0301x; 1.0301x over previous
//
#include <hip/hip_runtime.h>

// Problem constants (from reference): R=128, T=4096, M=32768, N=4096, L=16384
#define T_DIM 4096
#define R_DIM 128
#define M_DIM 32768
#define N_DIM 4096
#define L_DIM 16384

typedef __attribute__((ext_vector_type(8))) short short8;   // 8 x bf16 (4 VGPRs)
typedef __attribute__((ext_vector_type(4))) short short4_;  // 4 x bf16 (2 VGPRs)
typedef __attribute__((ext_vector_type(4))) float float4_;  // 4 x f32 acc

__device__ __forceinline__ unsigned short f2bf(float f) {
    // round-to-nearest-even fp32 -> bf16 (inputs finite)
    unsigned int u = __float_as_uint(f);
    unsigned int r = (u + 0x7fffu + ((u >> 16) & 1u)) >> 16;
    return (unsigned short)r;
}

// ---------------------------------------------------------------------------
// 1) x_pos = relu(x) -> xpos; Xt[t][k] = bf16(x_pos[k][t]) via LDS transpose
//    so both the global read (along t) and the Xt write (along k) coalesce.
//    grid = T/64 blocks; each block transposes a [128 k][64 t] tile.
__global__ __launch_bounds__(256) void prep_x(const float* __restrict__ x,
                                              float* __restrict__ xpos,
                                              unsigned short* __restrict__ Xt) {
    __shared__ unsigned short lds[64][130];   // pad 130: write/read both 2-way (free)
    const int tid = threadIdx.x;
    const int t0 = blockIdx.x * 64;
    #pragma unroll
    for (int it = 0; it < 32; it++) {
        int idx = it * 256 + tid;            // [0, 8192)
        int k = idx >> 6;                    // [0, 128)
        int tt = idx & 63;
        float v = fmaxf(x[k * T_DIM + t0 + tt], 0.0f);   // 256B coalesced
        xpos[k * T_DIM + t0 + tt] = v;                    // 256B coalesced
        lds[tt][k] = f2bf(v);
    }
    __syncthreads();
    const int w = tid >> 6, lane = tid & 63;
    #pragma unroll
    for (int rep = 0; rep < 16; rep++) {
        int row = w * 16 + rep;              // t-row within tile
        unsigned int lo = lds[row][2 * lane];
        unsigned int hi = lds[row][2 * lane + 1];
        // 64 lanes x 4B = 256B contiguous per t-row
        *(unsigned int*)(Xt + (size_t)(t0 + row) * R_DIM + 2 * lane) = lo | (hi << 16);
    }
}

// ---------------------------------------------------------------------------
// 2) Ab = bf16(A); B_seg[node_ids[m]][k..k+3] += A[m][k..k+3]  (float4 per thread)
__global__ __launch_bounds__(256) void cast_A_seg(const float* __restrict__ A,
                                                  const int* __restrict__ node_ids,
                                                  unsigned short* __restrict__ Ab,
                                                  float* __restrict__ Bseg) {
    int id = blockIdx.x * 256 + threadIdx.x;     // < M*R/4 = 1048576
    int m = id >> 5;
    int k = (id & 31) << 2;
    float4 v = *(const float4*)(A + (size_t)m * R_DIM + k);   // 1KB/wave coalesced
    short4_ b;
    b.x = (short)f2bf(v.x); b.y = (short)f2bf(v.y);
    b.z = (short)f2bf(v.z); b.w = (short)f2bf(v.w);
    *(short4_*)(Ab + (size_t)m * R_DIM + k) = b;              // 512B/wave coalesced
    float* dst = Bseg + (size_t)node_ids[m] * R_DIM + k;
    atomicAdd(dst + 0, v.x);
    atomicAdd(dst + 1, v.y);
    atomicAdd(dst + 2, v.z);
    atomicAdd(dst + 3, v.w);
}

// ---------------------------------------------------------------------------
// 3) Bb = bf16(B_seg), float4-vectorized
__global__ __launch_bounds__(256) void cast_Bseg(const float* __restrict__ Bseg,
                                                 unsigned short* __restrict__ Bb) {
    int id = blockIdx.x * 256 + threadIdx.x;     // < N*R/4 = 131072
    float4 v = *(const float4*)(Bseg + (size_t)id * 4);
    short4_ b;
    b.x = (short)f2bf(v.x); b.y = (short)f2bf(v.y);
    b.z = (short)f2bf(v.z); b.w = (short)f2bf(v.w);
    *(short4_*)(Bb + (size_t)id * 4) = b;
}

// ---------------------------------------------------------------------------
// 4) gcoef[n] = sum_{l: row_node[l]=n} t0*alpha*radio * (1/cap)^beta
//    cterm += t0*radio (wave-reduced).
//    Key identity: (flow*rcap)^beta = flow^beta * rcap^beta  (clamp at 1e-6
//    only binds when flow ~ 0, where both forms contribute < 1e-8).
__global__ __launch_bounds__(256) void prep_lw(const float* __restrict__ t0,
                                               const float* __restrict__ cap,
                                               const float* __restrict__ radio,
                                               const float* __restrict__ alpha_raw,
                                               const float* __restrict__ beta_raw,
                                               const int* __restrict__ row_node,
                                               float* __restrict__ gcoef,
                                               float* __restrict__ cterm) {
    int l = blockIdx.x * 256 + threadIdx.x;      // < 16384
    float alpha = 0.01f + 0.99f / (1.0f + expf(-alpha_raw[0]));
    float beta  = 1.0f + 7.0f  / (1.0f + expf(-beta_raw[0]));
    float tv = t0[l], rv = radio[l];
    float rc = 1.0f / cap[l];                    // cap in [500,1500] -> rc > 0
    float wv = tv * alpha * rv;
    float g = wv * __builtin_amdgcn_exp2f(beta * __builtin_amdgcn_logf(rc));
    atomicAdd(gcoef + row_node[l], g);
    float p = tv * rv;
    #pragma unroll
    for (int off = 32; off > 0; off >>= 1) p += __shfl_down(p, off, 64);
    if ((threadIdx.x & 63) == 0) atomicAdd(cterm, p);
}

// ---------------------------------------------------------------------------
// 5) y[t] = cterm   (atomics from the fused GEMM accumulate on top)
__global__ __launch_bounds__(256) void y_init(const float* __restrict__ cterm,
                                              float* __restrict__ y) {
    int t = blockIdx.x * 256 + threadIdx.x;
    y[t] = cterm[0];
}

// ---------------------------------------------------------------------------
// 6) C[M x T] = Am[M x 128](bf16) @ Xt^T  (Xt stored [T x 128] k-contig)
//    grid = (T/128, M/128); block = 256 (4 waves, 2x2), wave tile 64x64.
//    XCD-aware chunked swizzle: each XCD gets contiguous by-rows -> A-tiles
//    stay resident in that XCD's L2 instead of being re-fetched 8x.
__global__ __launch_bounds__(256) void gemm_mfma(const unsigned short* __restrict__ Am,
                                                 const unsigned short* __restrict__ Xt,
                                                 float* __restrict__ C) {
    const int nwg  = gridDim.x * gridDim.y;                  // divisible by 8
    const int orig = blockIdx.y * gridDim.x + blockIdx.x;
    const int cpx  = nwg >> 3;
    const int swz  = (orig & 7) * cpx + (orig >> 3);
    const int bx   = swz & 31;                               // gridDim.x == 32
    const int by   = swz >> 5;

    const int lane = threadIdx.x & 63;
    const int wid  = threadIdx.x >> 6;
    const int quad = lane >> 4;
    const int l16  = lane & 15;
    const int mBase = by * 128 + (wid & 1) * 64;
    const int tBase = bx * 128 + (wid >> 1) * 64;

    float4_ acc[4][4];
    #pragma unroll
    for (int i = 0; i < 4; i++)
        #pragma unroll
        for (int j = 0; j < 4; j++)
            acc[i][j] = (float4_)(0.0f);

    #pragma unroll
    for (int ks = 0; ks < 4; ks++) {
        const int k0 = ks * 32 + quad * 8;
        short8 a[4], b[4];
        #pragma unroll
        for (int i = 0; i < 4; i++) {
            size_t m = (size_t)(mBase + i * 16 + l16);
            a[i] = *(const short8*)(Am + m * R_DIM + k0);
        }
        #pragma unroll
        for (int j = 0; j < 4; j++) {
            size_t t = (size_t)(tBase + j * 16 + l16);
            b[j] = *(const short8*)(Xt + t * R_DIM + k0);
        }
        #pragma unroll
        for (int i = 0; i < 4; i++)
            #pragma unroll
            for (int j = 0; j < 4; j++)
                acc[i][j] = __builtin_amdgcn_mfma_f32_16x16x32_bf16(a[i], b[j], acc[i][j], 0, 0, 0);
    }

    // C/D layout: row = quad*4 + reg, col = l16 (verified m89/m91)
    #pragma unroll
    for (int i = 0; i < 4; i++) {
        int row0 = mBase + i * 16 + quad * 4;
        #pragma unroll
        for (int j = 0; j < 4; j++) {
            int col = tBase + j * 16 + l16;
            #pragma unroll
            for (int r = 0; r < 4; r++) {
                C[(size_t)(row0 + r) * T_DIM + col] = acc[i][j][r];
            }
        }
    }
}

// ---------------------------------------------------------------------------
// 7) Fused: nflow = Bseg @ x_pos, then y[t] += sum_n gcoef[n] * nflow[n][t]^beta
//    directly from the accumulator registers — nflow is never materialized.
//    Lane layout: col = l16 (fixed per lane), rows = quad*4+r -> lanes
//    {l16, l16+16, l16+32, l16+48} share a column; shfl_xor(16),(32) reduces.
__global__ __launch_bounds__(256) void gemm_nflow_y(const unsigned short* __restrict__ Bb,
                                                    const unsigned short* __restrict__ Xt,
                                                    const float* __restrict__ gcoef,
                                                    const float* __restrict__ beta_raw,
                                                    float* __restrict__ y) {
    const int nwg  = gridDim.x * gridDim.y;                  // 1024
    const int orig = blockIdx.y * gridDim.x + blockIdx.x;
    const int cpx  = nwg >> 3;
    const int swz  = (orig & 7) * cpx + (orig >> 3);
    const int bx   = swz & 31;                               // gridDim.x == 32
    const int by   = swz >> 5;

    const int lane = threadIdx.x & 63;
    const int wid  = threadIdx.x >> 6;
    const int quad = lane >> 4;
    const int l16  = lane & 15;
    const int bRow  = by * 128;
    const int mBase = bRow + (wid & 1) * 64;
    const int tBase = bx * 128 + (wid >> 1) * 64;

    __shared__ float gc[128];
    if (threadIdx.x < 128) gc[threadIdx.x] = gcoef[bRow + threadIdx.x];

    float4_ acc[4][4];
    #pragma unroll
    for (int i = 0; i < 4; i++)
        #pragma unroll
        for (int j = 0; j < 4; j++)
            acc[i][j] = (float4_)(0.0f);

    #pragma unroll
    for (int ks = 0; ks < 4; ks++) {
        const int k0 = ks * 32 + quad * 8;
        short8 a[4], b[4];
        #pragma unroll
        for (int i = 0; i < 4; i++) {
            size_t m = (size_t)(mBase + i * 16 + l16);
            a[i] = *(const short8*)(Bb + m * R_DIM + k0);
        }
        #pragma unroll
        for (int j = 0; j < 4; j++) {
            size_t t = (size_t)(tBase + j * 16 + l16);
            b[j] = *(const short8*)(Xt + t * R_DIM + k0);
        }
        #pragma unroll
        for (int i = 0; i < 4; i++)
            #pragma unroll
            for (int j = 0; j < 4; j++)
                acc[i][j] = __builtin_amdgcn_mfma_f32_16x16x32_bf16(a[i], b[j], acc[i][j], 0, 0, 0);
    }

    __syncthreads();   // gc ready
    float beta = 1.0f + 7.0f / (1.0f + expf(-beta_raw[0]));
    float p[4] = {0.0f, 0.0f, 0.0f, 0.0f};
    #pragma unroll
    for (int i = 0; i < 4; i++) {
        int r0 = (wid & 1) * 64 + i * 16 + quad * 4;         // row - bRow
        #pragma unroll
        for (int r = 0; r < 4; r++) {
            float g = gc[r0 + r];
            #pragma unroll
            for (int j = 0; j < 4; j++) {
                float f = acc[i][j][r];                      // flow >= 0
                // flow^beta = 2^(beta*log2(flow)); flow=0 underflows to 0 (correct)
                float pw = __builtin_amdgcn_exp2f(beta * __builtin_amdgcn_logf(fmaxf(f, 1e-30f)));
                p[j] += g * pw;
            }
        }
    }
    #pragma unroll
    for (int j = 0; j < 4; j++) {
        p[j] += __shfl_xor(p[j], 16, 64);
        p[j] += __shfl_xor(p[j], 32, 64);
        if (quad == 0) atomicAdd(&y[tBase + j * 16 + l16], p[j]);
    }
}

// ---------------------------------------------------------------------------
extern "C" void kernel_launch(void* const* d_in, const int* in_sizes, int n_in,
                              void* d_out, int out_size, void* d_ws, size_t ws_size,
                              hipStream_t stream) {
    const float* x         = (const float*)d_in[0];
    const float* A         = (const float*)d_in[1];
    const float* t0        = (const float*)d_in[2];
    const float* cap       = (const float*)d_in[3];
    const float* radio     = (const float*)d_in[4];
    const float* alpha_raw = (const float*)d_in[5];
    const float* beta_raw  = (const float*)d_in[6];
    const int*   node_ids  = (const int*)d_in[7];
    const int*   row_node  = (const int*)d_in[8];

    float* out   = (float*)d_out;
    float* xpos  = out;                                   // R*T   = 524288
    float* cpred = out + (size_t)R_DIM * T_DIM;           // M*T   = 134217728
    float* y     = cpred + (size_t)M_DIM * T_DIM;         // T     = 4096

    char* ws = (char*)d_ws;
    unsigned short* Xt    = (unsigned short*)(ws);                       // 1 MB
    unsigned short* Ab    = (unsigned short*)(ws + (1u << 20));          // 8 MB
    unsigned short* Bb    = (unsigned short*)(ws + (9u << 20));          // 1 MB
    float*          Bseg  = (float*)(ws + (10u << 20));                  // 2 MB
    float*          gcoef = (float*)(ws + (12u << 20));                  // 16 KB
    float*          csum  = gcoef + N_DIM;                               // 4 B

    // zero the atomic-accumulated regions (ws/d_out are poisoned each call)
    (void)hipMemsetAsync(Bseg, 0, (size_t)N_DIM * R_DIM * sizeof(float), stream);
    (void)hipMemsetAsync(gcoef, 0, (size_t)(N_DIM + 1) * sizeof(float), stream);

    prep_x    <<<dim3(T_DIM / 64), 256, 0, stream>>>(x, xpos, Xt);
    cast_A_seg<<<dim3((M_DIM * R_DIM / 4) / 256), 256, 0, stream>>>(A, node_ids, Ab, Bseg);
    cast_Bseg <<<dim3((N_DIM * R_DIM / 4) / 256), 256, 0, stream>>>(Bseg, Bb);
    prep_lw   <<<dim3(L_DIM / 256), 256, 0, stream>>>(t0, cap, radio, alpha_raw,
                                                      beta_raw, row_node, gcoef, csum);
    y_init    <<<dim3(T_DIM / 256), 256, 0, stream>>>(csum, y);

    // c_pred = A @ x_pos   [32768 x 4096]
    gemm_mfma<<<dim3(T_DIM / 128, M_DIM / 128), 256, 0, stream>>>(Ab, Xt, cpred);
    // y += sum_n gcoef[n] * (Bseg @ x_pos)[n][t]^beta   (nflow never materialized)
    gemm_nflow_y<<<dim3(T_DIM / 128, N_DIM / 128), 256, 0, stream>>>(Bb, Xt, gcoef, beta_raw, y);
}

// Round 3
// 647.858 us; speedup vs baseline: 1.1128x; 1.0803x over previous
//
#include <hip/hip_runtime.h>

// Problem constants (from reference): R=128, T=4096, M=32768, N=4096, L=16384
#define T_DIM 4096
#define R_DIM 128
#define M_DIM 32768
#define N_DIM 4096
#define L_DIM 16384
#define BUCKET_CAP 64   // max rows per node; P(overflow) ~ 1e-18 for Poisson(8)

typedef __attribute__((ext_vector_type(8))) short short8;   // 8 x bf16 (4 VGPRs)
typedef __attribute__((ext_vector_type(4))) short short4_;  // 4 x bf16 (2 VGPRs)
typedef __attribute__((ext_vector_type(4))) float float4_;  // 4 x f32 acc

__device__ __forceinline__ unsigned short f2bf(float f) {
    // round-to-nearest-even fp32 -> bf16 (inputs finite)
    unsigned int u = __float_as_uint(f);
    unsigned int r = (u + 0x7fffu + ((u >> 16) & 1u)) >> 16;
    return (unsigned short)r;
}

// ---------------------------------------------------------------------------
// 1) x_pos = relu(x) -> xpos; Xt[t][k] = bf16(x_pos[k][t]) via LDS transpose
//    so both the global read (along t) and the Xt write (along k) coalesce.
//    grid = T/64 blocks; each block transposes a [128 k][64 t] tile.
__global__ __launch_bounds__(256) void prep_x(const float* __restrict__ x,
                                              float* __restrict__ xpos,
                                              unsigned short* __restrict__ Xt) {
    __shared__ unsigned short lds[64][130];   // pad 130: write/read both 2-way (free)
    const int tid = threadIdx.x;
    const int t0 = blockIdx.x * 64;
    #pragma unroll
    for (int it = 0; it < 32; it++) {
        int idx = it * 256 + tid;            // [0, 8192)
        int k = idx >> 6;                    // [0, 128)
        int tt = idx & 63;
        float v = fmaxf(x[k * T_DIM + t0 + tt], 0.0f);    // 256B coalesced
        __builtin_nontemporal_store(v, &xpos[k * T_DIM + t0 + tt]);  // output-only
        lds[tt][k] = f2bf(v);
    }
    __syncthreads();
    const int w = tid >> 6, lane = tid & 63;
    #pragma unroll
    for (int rep = 0; rep < 16; rep++) {
        int row = w * 16 + rep;              // t-row within tile
        unsigned int lo = lds[row][2 * lane];
        unsigned int hi = lds[row][2 * lane + 1];
        // 64 lanes x 4B = 256B contiguous per t-row
        *(unsigned int*)(Xt + (size_t)(t0 + row) * R_DIM + 2 * lane) = lo | (hi << 16);
    }
}

// ---------------------------------------------------------------------------
// 2) Ab = bf16(A) — pure streaming cast, 32B in / 16B out per thread.
//    (The old version did 4 contended fp32 atomicAdds per thread to build
//    Bseg — 4.19M atomics, the hypothesized dominant cost. Removed.)
__global__ __launch_bounds__(256) void cast_A(const float* __restrict__ A,
                                              unsigned short* __restrict__ Ab) {
    size_t id = (size_t)blockIdx.x * 256 + threadIdx.x;   // < M*R/8 = 524288
    float4 v0 = *(const float4*)(A + id * 8);
    float4 v1 = *(const float4*)(A + id * 8 + 4);
    short8 b;
    b[0] = (short)f2bf(v0.x); b[1] = (short)f2bf(v0.y);
    b[2] = (short)f2bf(v0.z); b[3] = (short)f2bf(v0.w);
    b[4] = (short)f2bf(v1.x); b[5] = (short)f2bf(v1.y);
    b[6] = (short)f2bf(v1.z); b[7] = (short)f2bf(v1.w);
    *(short8*)(Ab + id * 8) = b;
}

// ---------------------------------------------------------------------------
// 3) Bucket build: bucket[n][slot] = m for each m with node_ids[m] = n.
//    One atomic per movement row (32K total, vs 4.19M before).
__global__ __launch_bounds__(256) void scatter_nodes(const int* __restrict__ node_ids,
                                                     int* __restrict__ cnt,
                                                     int* __restrict__ bucket) {
    int m = blockIdx.x * 256 + threadIdx.x;   // < 32768
    int n = node_ids[m];
    int slot = atomicAdd(cnt + n, 1);
    if (slot < BUCKET_CAP) bucket[n * BUCKET_CAP + slot] = m;
}

// ---------------------------------------------------------------------------
// 4) Bb[n][k] = bf16( sum_{m in bucket[n]} A[m][k] ).  Two nodes per block;
//    per bucket row: 128 threads x 4B = 512B coalesced read of A (L3-hot).
__global__ __launch_bounds__(256) void bseg_gather(const float* __restrict__ A,
                                                   const int* __restrict__ cnt,
                                                   const int* __restrict__ bucket,
                                                   unsigned short* __restrict__ Bb) {
    int n = blockIdx.x * 2 + (threadIdx.x >> 7);   // < 4096
    int k = threadIdx.x & 127;
    int c = cnt[n];
    c = (c > BUCKET_CAP) ? BUCKET_CAP : c;
    float acc = 0.0f;
    for (int s = 0; s < c; s++) {
        int m = bucket[n * BUCKET_CAP + s];        // wave-uniform -> scalar load
        acc += A[(size_t)m * R_DIM + k];
    }
    Bb[(size_t)n * R_DIM + k] = f2bf(acc);
}

// ---------------------------------------------------------------------------
// 5) gcoef[n] = sum_{l: row_node[l]=n} t0*alpha*radio * (1/cap)^beta
//    cterm += t0*radio (wave-reduced).
//    Key identity: (flow*rcap)^beta = flow^beta * rcap^beta  (clamp at 1e-6
//    only binds when flow ~ 0, where both forms contribute < 1e-5).
__global__ __launch_bounds__(256) void prep_lw(const float* __restrict__ t0,
                                               const float* __restrict__ cap,
                                               const float* __restrict__ radio,
                                               const float* __restrict__ alpha_raw,
                                               const float* __restrict__ beta_raw,
                                               const int* __restrict__ row_node,
                                               float* __restrict__ gcoef,
                                               float* __restrict__ cterm) {
    int l = blockIdx.x * 256 + threadIdx.x;      // < 16384
    float alpha = 0.01f + 0.99f / (1.0f + expf(-alpha_raw[0]));
    float beta  = 1.0f + 7.0f  / (1.0f + expf(-beta_raw[0]));
    float tv = t0[l], rv = radio[l];
    float rc = 1.0f / cap[l];                    // cap in [500,1500] -> rc > 0
    float wv = tv * alpha * rv;
    float g = wv * __builtin_amdgcn_exp2f(beta * __builtin_amdgcn_logf(rc));
    atomicAdd(gcoef + row_node[l], g);
    float p = tv * rv;
    #pragma unroll
    for (int off = 32; off > 0; off >>= 1) p += __shfl_down(p, off, 64);
    if ((threadIdx.x & 63) == 0) atomicAdd(cterm, p);
}

// ---------------------------------------------------------------------------
// 6) y[t] = cterm   (atomics from the fused GEMM accumulate on top)
__global__ __launch_bounds__(256) void y_init(const float* __restrict__ cterm,
                                              float* __restrict__ y) {
    int t = blockIdx.x * 256 + threadIdx.x;
    y[t] = cterm[0];
}

// ---------------------------------------------------------------------------
// 7) C[M x T] = Am[M x 128](bf16) @ Xt^T  (Xt stored [T x 128] k-contig)
//    grid = (T/128, M/128); block = 256 (4 waves, 2x2), wave tile 64x64.
//    XCD-aware chunked swizzle keeps each XCD's A-panel L2-resident.
//    C stores are nontemporal: 512MB streamed out, never re-read — keeps
//    Ab/Xt operand lines from being evicted by write-allocate.
__global__ __launch_bounds__(256) void gemm_mfma(const unsigned short* __restrict__ Am,
                                                 const unsigned short* __restrict__ Xt,
                                                 float* __restrict__ C) {
    const int nwg  = gridDim.x * gridDim.y;                  // divisible by 8
    const int orig = blockIdx.y * gridDim.x + blockIdx.x;
    const int cpx  = nwg >> 3;
    const int swz  = (orig & 7) * cpx + (orig >> 3);
    const int bx   = swz & 31;                               // gridDim.x == 32
    const int by   = swz >> 5;

    const int lane = threadIdx.x & 63;
    const int wid  = threadIdx.x >> 6;
    const int quad = lane >> 4;
    const int l16  = lane & 15;
    const int mBase = by * 128 + (wid & 1) * 64;
    const int tBase = bx * 128 + (wid >> 1) * 64;

    float4_ acc[4][4];
    #pragma unroll
    for (int i = 0; i < 4; i++)
        #pragma unroll
        for (int j = 0; j < 4; j++)
            acc[i][j] = (float4_)(0.0f);

    #pragma unroll
    for (int ks = 0; ks < 4; ks++) {
        const int k0 = ks * 32 + quad * 8;
        short8 a[4], b[4];
        #pragma unroll
        for (int i = 0; i < 4; i++) {
            size_t m = (size_t)(mBase + i * 16 + l16);
            a[i] = *(const short8*)(Am + m * R_DIM + k0);
        }
        #pragma unroll
        for (int j = 0; j < 4; j++) {
            size_t t = (size_t)(tBase + j * 16 + l16);
            b[j] = *(const short8*)(Xt + t * R_DIM + k0);
        }
        #pragma unroll
        for (int i = 0; i < 4; i++)
            #pragma unroll
            for (int j = 0; j < 4; j++)
                acc[i][j] = __builtin_amdgcn_mfma_f32_16x16x32_bf16(a[i], b[j], acc[i][j], 0, 0, 0);
    }

    // C/D layout: row = quad*4 + reg, col = l16 (verified m89/m91)
    #pragma unroll
    for (int i = 0; i < 4; i++) {
        int row0 = mBase + i * 16 + quad * 4;
        #pragma unroll
        for (int j = 0; j < 4; j++) {
            int col = tBase + j * 16 + l16;
            #pragma unroll
            for (int r = 0; r < 4; r++) {
                __builtin_nontemporal_store(acc[i][j][r], &C[(size_t)(row0 + r) * T_DIM + col]);
            }
        }
    }
}

// ---------------------------------------------------------------------------
// 8) Fused: nflow = Bseg @ x_pos, then y[t] += sum_n gcoef[n] * nflow[n][t]^beta
//    directly from the accumulator registers — nflow is never materialized.
//    Lane layout: col = l16 (fixed per lane), rows = quad*4+r -> lanes
//    {l16, l16+16, l16+32, l16+48} share a column; shfl_xor(16),(32) reduces.
__global__ __launch_bounds__(256) void gemm_nflow_y(const unsigned short* __restrict__ Bb,
                                                    const unsigned short* __restrict__ Xt,
                                                    const float* __restrict__ gcoef,
                                                    const float* __restrict__ beta_raw,
                                                    float* __restrict__ y) {
    const int nwg  = gridDim.x * gridDim.y;                  // 1024
    const int orig = blockIdx.y * gridDim.x + blockIdx.x;
    const int cpx  = nwg >> 3;
    const int swz  = (orig & 7) * cpx + (orig >> 3);
    const int bx   = swz & 31;                               // gridDim.x == 32
    const int by   = swz >> 5;

    const int lane = threadIdx.x & 63;
    const int wid  = threadIdx.x >> 6;
    const int quad = lane >> 4;
    const int l16  = lane & 15;
    const int bRow  = by * 128;
    const int mBase = bRow + (wid & 1) * 64;
    const int tBase = bx * 128 + (wid >> 1) * 64;

    __shared__ float gc[128];
    if (threadIdx.x < 128) gc[threadIdx.x] = gcoef[bRow + threadIdx.x];

    float4_ acc[4][4];
    #pragma unroll
    for (int i = 0; i < 4; i++)
        #pragma unroll
        for (int j = 0; j < 4; j++)
            acc[i][j] = (float4_)(0.0f);

    #pragma unroll
    for (int ks = 0; ks < 4; ks++) {
        const int k0 = ks * 32 + quad * 8;
        short8 a[4], b[4];
        #pragma unroll
        for (int i = 0; i < 4; i++) {
            size_t m = (size_t)(mBase + i * 16 + l16);
            a[i] = *(const short8*)(Bb + m * R_DIM + k0);
        }
        #pragma unroll
        for (int j = 0; j < 4; j++) {
            size_t t = (size_t)(tBase + j * 16 + l16);
            b[j] = *(const short8*)(Xt + t * R_DIM + k0);
        }
        #pragma unroll
        for (int i = 0; i < 4; i++)
            #pragma unroll
            for (int j = 0; j < 4; j++)
                acc[i][j] = __builtin_amdgcn_mfma_f32_16x16x32_bf16(a[i], b[j], acc[i][j], 0, 0, 0);
    }

    __syncthreads();   // gc ready
    float beta = 1.0f + 7.0f / (1.0f + expf(-beta_raw[0]));
    float p[4] = {0.0f, 0.0f, 0.0f, 0.0f};
    #pragma unroll
    for (int i = 0; i < 4; i++) {
        int r0 = (wid & 1) * 64 + i * 16 + quad * 4;         // row - bRow
        #pragma unroll
        for (int r = 0; r < 4; r++) {
            float g = gc[r0 + r];
            #pragma unroll
            for (int j = 0; j < 4; j++) {
                float f = acc[i][j][r];                      // flow >= 0
                // flow^beta = 2^(beta*log2(flow)); flow=0 underflows to 0 (correct)
                float pw = __builtin_amdgcn_exp2f(beta * __builtin_amdgcn_logf(fmaxf(f, 1e-30f)));
                p[j] += g * pw;
            }
        }
    }
    #pragma unroll
    for (int j = 0; j < 4; j++) {
        p[j] += __shfl_xor(p[j], 16, 64);
        p[j] += __shfl_xor(p[j], 32, 64);
        if (quad == 0) atomicAdd(&y[tBase + j * 16 + l16], p[j]);
    }
}

// ---------------------------------------------------------------------------
extern "C" void kernel_launch(void* const* d_in, const int* in_sizes, int n_in,
                              void* d_out, int out_size, void* d_ws, size_t ws_size,
                              hipStream_t stream) {
    const float* x         = (const float*)d_in[0];
    const float* A         = (const float*)d_in[1];
    const float* t0        = (const float*)d_in[2];
    const float* cap       = (const float*)d_in[3];
    const float* radio     = (const float*)d_in[4];
    const float* alpha_raw = (const float*)d_in[5];
    const float* beta_raw  = (const float*)d_in[6];
    const int*   node_ids  = (const int*)d_in[7];
    const int*   row_node  = (const int*)d_in[8];

    float* out   = (float*)d_out;
    float* xpos  = out;                                   // R*T   = 524288
    float* cpred = out + (size_t)R_DIM * T_DIM;           // M*T   = 134217728
    float* y     = cpred + (size_t)M_DIM * T_DIM;         // T     = 4096

    char* ws = (char*)d_ws;
    unsigned short* Xt     = (unsigned short*)(ws);                      // 1 MB
    unsigned short* Ab     = (unsigned short*)(ws + (1u << 20));         // 8 MB
    unsigned short* Bb     = (unsigned short*)(ws + (9u << 20));         // 1 MB
    int*            cnt    = (int*)(ws + (10u << 20));                   // 16 KB
    float*          gcoef  = (float*)(ws + (10u << 20) + N_DIM * 4);     // 16 KB
    float*          csum   = gcoef + N_DIM;                              // 4 B
    int*            bucket = (int*)(ws + (11u << 20));                   // 1 MB

    // zero the atomic-accumulated regions in one memset (cnt|gcoef|csum contiguous)
    (void)hipMemsetAsync(cnt, 0, (size_t)(2 * N_DIM + 1) * 4, stream);

    prep_x       <<<dim3(T_DIM / 64), 256, 0, stream>>>(x, xpos, Xt);
    cast_A       <<<dim3((M_DIM * R_DIM / 8) / 256), 256, 0, stream>>>(A, Ab);
    scatter_nodes<<<dim3(M_DIM / 256), 256, 0, stream>>>(node_ids, cnt, bucket);
    prep_lw      <<<dim3(L_DIM / 256), 256, 0, stream>>>(t0, cap, radio, alpha_raw,
                                                         beta_raw, row_node, gcoef, csum);
    y_init       <<<dim3(T_DIM / 256), 256, 0, stream>>>(csum, y);
    bseg_gather  <<<dim3(N_DIM / 2), 256, 0, stream>>>(A, cnt, bucket, Bb);

    // c_pred = A @ x_pos   [32768 x 4096]
    gemm_mfma<<<dim3(T_DIM / 128, M_DIM / 128), 256, 0, stream>>>(Ab, Xt, cpred);
    // y += sum_n gcoef[n] * (Bseg @ x_pos)[n][t]^beta   (nflow never materialized)
    gemm_nflow_y<<<dim3(T_DIM / 128, N_DIM / 128), 256, 0, stream>>>(Bb, Xt, gcoef, beta_raw, y);
}